// Round 7
// baseline (437.516 us; speedup 1.0000x reference)
//
#include <hip/hip_runtime.h>
#include <hip/hip_fp16.h>
#include <math.h>

#define N_NODES 100000
#define N_PART  5000
#define N_EDGES 1000000
#define D_NODE  128
#define D_PART  128
#define D_ATT   20
#define SORTB   128   // cooperative sort blocks
#define EPB     ((N_EDGES + SORTB - 1) / SORTB)

// mega_setup block ranges
#define CONV_END  12500
#define DOT_END   (CONV_END + 192)    // 128k x 384c dot entries
#define COPY_END  (DOT_END + 256)     // 128kp x 512 copy entries
#define ZF_END    (COPY_END + 64)     // 16384 zero-fill (k<128, g=3)
#define BINIT_END (ZF_END + 2)        // 512 binit/bvec4 entries
#define MB_END    (BINIT_END + 128)   // 32768 M entries
#define MK_END    (MB_END + 1)        // mk/moff/ck
#define SETUP_GRID MK_END

__device__ __forceinline__ float sigmoid_(float x) { return 1.f / (1.f + __expf(-x)); }
__device__ __forceinline__ float tanh_(float x)    { return 1.f - 2.f / (__expf(2.f * x) + 1.f); }

// ---------------------------------------------------------------------------
// Mega setup: all independent precompute in one launch, dispatched by block id.
//  - fp16 convert of nodes
//  - Wbig2[k][j*4+g]: gate-interleaved combined GRU weights (K=256 x 512)
//      g: 0=r(sum), 1=z(sum), 2=i_n, 3=h_n
//      k<128 (agg side):  g<3: dot(valW[k,:], Wih[g*128+j,:]);  g=3: 0
//      k>=128 (h side):   g<2: Whh[g*128+j][k-128]; g=2: 0; g=3: Whh[256+j][k-128]
//  - binit[j*4+g]: constant bias per gate; bvec4[j*4+g]: att_sum multiplier
//  - M[k][j] = sum_a qW[k][a]*keyW[j][a]  (query fold, K=256 GEMM weights)
//  - mk[k] = qW[k,:].keyb ; ck = qb.keyb ; moff[j] = qb . keyW[j,:]
// ---------------------------------------------------------------------------
__global__ __launch_bounds__(256) void mega_setup(
    const float* __restrict__ nodes, __half* __restrict__ nh, int use_f16,
    const float* __restrict__ valW, const float* __restrict__ Wih,
    const float* __restrict__ Whh, const float* __restrict__ valb,
    const float* __restrict__ bih, const float* __restrict__ bhh,
    const float* __restrict__ qW, const float* __restrict__ qb,
    const float* __restrict__ keyW, const float* __restrict__ keyb,
    float* __restrict__ Wbig2, float* __restrict__ binit,
    float* __restrict__ bvec4, float* __restrict__ M,
    float* __restrict__ mkbuf)
{
    int b = blockIdx.x;
    int t = threadIdx.x;

    if (b < CONV_END) {
        if (!use_f16) return;
        int i = b * 256 + t;                     // one float4 per thread
        float4 v = ((const float4*)nodes)[i];
        __half2 a = __floats2half2_rn(v.x, v.y);
        __half2 c = __floats2half2_rn(v.z, v.w);
        ((__half2*)nh)[i * 2]     = a;
        ((__half2*)nh)[i * 2 + 1] = c;
    } else if (b < DOT_END) {
        int idx = (b - CONV_END) * 256 + t;      // 49152 = 128k x 384c
        int k = idx / 384, c = idx % 384;
        const float* va = valW + (size_t)k * 128;
        const float* wb = Wih + (size_t)c * 128;
        float acc = 0.f;
        #pragma unroll 8
        for (int m = 0; m < 128; m++) acc += va[m] * wb[m];
        Wbig2[(size_t)k * 512 + (c & 127) * 4 + (c >> 7)] = acc;
    } else if (b < COPY_END) {
        int idx = (b - DOT_END) * 256 + t;       // 65536 = 128kp x 512
        int kp = idx >> 9, rem = idx & 511;
        int j = rem >> 2, g = rem & 3;
        float v = 0.f;
        if (g < 2)       v = Whh[(size_t)(g * 128 + j) * 128 + kp];
        else if (g == 3) v = Whh[(size_t)(256 + j) * 128 + kp];
        Wbig2[(size_t)(128 + kp) * 512 + rem] = v;
    } else if (b < ZF_END) {
        int idx = (b - COPY_END) * 256 + t;      // 16384 = 128k x 128j
        int k = idx >> 7, j = idx & 127;
        Wbig2[(size_t)k * 512 + j * 4 + 3] = 0.f;
    } else if (b < BINIT_END) {
        int idx = (b - ZF_END) * 256 + t;        // 512 = 128j x 4g
        int j = idx >> 2, g = idx & 3;
        float bi;
        if (g == 0)      bi = bih[j] + bhh[j];
        else if (g == 1) bi = bih[128 + j] + bhh[128 + j];
        else if (g == 2) bi = bih[256 + j];
        else             bi = bhh[256 + j];
        binit[idx] = bi;
        float bv = 0.f;
        if (g < 3) {
            const float* wr = Wih + (size_t)(g * 128 + j) * 128;
            #pragma unroll 8
            for (int m = 0; m < 128; m++) bv += valb[m] * wr[m];
        }
        bvec4[idx] = bv;
    } else if (b < MB_END) {
        int idx = (b - BINIT_END) * 256 + t;     // 32768 = 256k x 128j
        int k = idx >> 7, j = idx & 127;
        const float* qr = qW + k * 20;
        const float* kr = keyW + j * 20;
        float acc = 0.f;
        #pragma unroll
        for (int a = 0; a < D_ATT; a++) acc += qr[a] * kr[a];
        M[idx] = acc;
    } else {
        // mk[0..256), ck at [256], moff at [260..388)
        {
            float acc = 0.f;
            const float* qr = qW + t * 20;
            #pragma unroll
            for (int a = 0; a < D_ATT; a++) acc += qr[a] * keyb[a];
            mkbuf[t] = acc;
        }
        if (t < 128) {
            float acc = 0.f;
            const float* kr = keyW + t * 20;
            #pragma unroll
            for (int a = 0; a < D_ATT; a++) acc += qb[a] * kr[a];
            mkbuf[260 + t] = acc;
        }
        if (t == 0) {
            float acc = 0.f;
            #pragma unroll
            for (int a = 0; a < D_ATT; a++) acc += qb[a] * keyb[a];
            mkbuf[256] = acc;
        }
    }
}

// ---------------------------------------------------------------------------
// Grid barrier among the first SORTB blocks (all co-resident by capacity).
// ---------------------------------------------------------------------------
__device__ __forceinline__ void gridbar(int* bar, int nblk) {
    __syncthreads();
    if (threadIdx.x == 0) {
        __threadfence();
        atomicAdd(bar, 1);
        while (__hip_atomic_load(bar, __ATOMIC_ACQUIRE, __HIP_MEMORY_SCOPE_AGENT) < nblk) {}
        __threadfence();
    }
    __syncthreads();
}

// ---------------------------------------------------------------------------
// Phase 2: blocks [0,128): 4-stage counting sort with grid barriers.
//          blocks [128,753): query-GEMM qk = [ph|gr] @ M + moff, qoff.
// ---------------------------------------------------------------------------
__global__ __launch_bounds__(256) void phase2_kernel(
    const int* __restrict__ src, const int* __restrict__ dst,
    const float* __restrict__ ph, const float* __restrict__ gr,
    const float* __restrict__ M, const float* __restrict__ mkbuf,
    int* __restrict__ blockhist, int* __restrict__ totals,
    int* __restrict__ offsets, int* __restrict__ ssrc,
    float* __restrict__ qk, float* __restrict__ qoff,
    int* __restrict__ bar)
{
    __shared__ char smem[20000];
    int t = threadIdx.x;

    if (blockIdx.x < SORTB) {
        int b = blockIdx.x;
        int* h = (int*)smem;
        // P1: per-block LDS histogram
        for (int i = t; i < N_PART; i += 256) h[i] = 0;
        __syncthreads();
        int beg = b * EPB, end = min(beg + EPB, N_EDGES);
        for (int e = beg + t; e < end; e += 256)
            atomicAdd(&h[dst[e]], 1);
        __syncthreads();
        for (int i = t; i < N_PART; i += 256)
            blockhist[(size_t)b * N_PART + i] = h[i];
        gridbar(&bar[0], SORTB);

        // P2: column scan (thread per dst over 128 blocks)
        int gid = b * 256 + t;
        if (gid < N_PART) {
            int run = 0;
            for (int bb = 0; bb < SORTB; bb++) {
                size_t idx = (size_t)bb * N_PART + gid;
                int v = blockhist[idx];
                blockhist[idx] = run;
                run += v;
            }
            totals[gid] = run;
        }
        gridbar(&bar[1], SORTB);

        // P3: exclusive scan of totals (block 0)
        if (b == 0) {
            __shared__ int ss[256];
            const int CH = 20;
            int sbeg = t * CH;
            int send = min(sbeg + CH, N_PART);
            int lsum = 0;
            for (int i = sbeg; i < send; i++) lsum += totals[i];
            ss[t] = lsum;
            __syncthreads();
            for (int off = 1; off < 256; off <<= 1) {
                int v = (t >= off) ? ss[t - off] : 0;
                __syncthreads();
                ss[t] += v;
                __syncthreads();
            }
            int base = ss[t] - lsum;
            for (int i = sbeg; i < send; i++) {
                offsets[i] = base;
                base += totals[i];
            }
            if (t == 0) offsets[N_PART] = N_EDGES;
        }
        gridbar(&bar[2], SORTB);

        // P4: scatter with LDS cursors (reuse h)
        for (int i = t; i < N_PART; i += 256)
            h[i] = offsets[i] + blockhist[(size_t)b * N_PART + i];
        __syncthreads();
        for (int e = beg + t; e < end; e += 256) {
            int d = dst[e];
            int pos = atomicAdd(&h[d], 1);
            ssrc[pos] = src[e];
        }
    } else {
        // query GEMM: 625 blocks x 8 particles
        float (*s_in)[256] = (float(*)[256])smem;
        int pbase = (blockIdx.x - SORTB) * 8;
        for (int f = t; f < 8 * 64; f += 256) {
            int pl = f >> 6, c4 = (f & 63) * 4;
            int p = pbase + pl;
            float4 v;
            if (c4 < 128) v = *(const float4*)(ph + (size_t)p * 128 + c4);
            else          v = *(const float4*)(gr + (size_t)p * 128 + (c4 - 128));
            *(float4*)&s_in[pl][c4] = v;
        }
        __syncthreads();
        int pl = t >> 5, jq = t & 31;
        int j4 = jq * 4;
        int p = pbase + pl;
        float4 acc = *(const float4*)(mkbuf + 260 + j4);   // moff
        #pragma unroll 4
        for (int k = 0; k < 256; k++) {
            float x = s_in[pl][k];
            float4 w = *(const float4*)(M + (size_t)k * 128 + j4);
            acc.x += x * w.x; acc.y += x * w.y; acc.z += x * w.z; acc.w += x * w.w;
        }
        *(float4*)(qk + (size_t)p * 128 + j4) = acc;
        if (jq == 0) {
            float o = mkbuf[256];  // ck
            for (int k = 0; k < 256; k++) o += s_in[pl][k] * mkbuf[k];
            qoff[p] = o;
        }
    }
}

// ---------------------------------------------------------------------------
// K3 fp16: quarter-wave (16 lanes x 16B = 8 halves) per edge (unchanged R6).
// ---------------------------------------------------------------------------
__global__ __launch_bounds__(256) void edge_agg_f16(
    const __half* __restrict__ nh, const float* __restrict__ qk,
    const float* __restrict__ qoff,
    const int* __restrict__ offsets, const int* __restrict__ ssrc,
    float* __restrict__ agg, float* __restrict__ att_sum)
{
    const float norm = 0.22360679774997896f;  // 1/sqrt(20)
    int p = blockIdx.x;
    int tid = threadIdx.x;
    int lane = tid & 63;
    int wave = tid >> 6;
    int lane16 = lane & 15;
    int col8 = lane16 * 8;

    float4 q0 = *(const float4*)(qk + (size_t)p * 128 + col8);
    float4 q1 = *(const float4*)(qk + (size_t)p * 128 + col8 + 4);
    float qo = qoff[p];
    int beg = offsets[p];
    int n = offsets[p + 1] - beg;

    float4 a0 = {0.f, 0.f, 0.f, 0.f};
    float4 a1 = {0.f, 0.f, 0.f, 0.f};
    float asum = 0.f;

    int i = wave * 8 + (lane >> 4);
    for (; i + 4 < n; i += 32) {
        int sA = ssrc[beg + i];
        int sB = ssrc[beg + i + 4];
        float4 rawA = *(const float4*)(nh + (size_t)sA * 128 + col8);
        float4 rawB = *(const float4*)(nh + (size_t)sB * 128 + col8);
        const __half2* hA = (const __half2*)&rawA;
        const __half2* hB = (const __half2*)&rawB;
        float2 xa0 = __half22float2(hA[0]), xa1 = __half22float2(hA[1]);
        float2 xa2 = __half22float2(hA[2]), xa3 = __half22float2(hA[3]);
        float2 xb0 = __half22float2(hB[0]), xb1 = __half22float2(hB[1]);
        float2 xb2 = __half22float2(hB[2]), xb3 = __half22float2(hB[3]);
        float dA = xa0.x * q0.x + xa0.y * q0.y + xa1.x * q0.z + xa1.y * q0.w
                 + xa2.x * q1.x + xa2.y * q1.y + xa3.x * q1.z + xa3.y * q1.w;
        float dB = xb0.x * q0.x + xb0.y * q0.y + xb1.x * q0.z + xb1.y * q0.w
                 + xb2.x * q1.x + xb2.y * q1.y + xb3.x * q1.z + xb3.y * q1.w;
        #pragma unroll
        for (int off = 1; off <= 8; off <<= 1) {
            dA += __shfl_xor(dA, off, 64);
            dB += __shfl_xor(dB, off, 64);
        }
        float attA = (dA + qo) * norm;
        float attB = (dB + qo) * norm;
        a0.x += attA * xa0.x + attB * xb0.x;
        a0.y += attA * xa0.y + attB * xb0.y;
        a0.z += attA * xa1.x + attB * xb1.x;
        a0.w += attA * xa1.y + attB * xb1.y;
        a1.x += attA * xa2.x + attB * xb2.x;
        a1.y += attA * xa2.y + attB * xb2.y;
        a1.z += attA * xa3.x + attB * xb3.x;
        a1.w += attA * xa3.y + attB * xb3.y;
        asum += attA + attB;
    }
    if (i < n) {
        int sA = ssrc[beg + i];
        float4 rawA = *(const float4*)(nh + (size_t)sA * 128 + col8);
        const __half2* hA = (const __half2*)&rawA;
        float2 xa0 = __half22float2(hA[0]), xa1 = __half22float2(hA[1]);
        float2 xa2 = __half22float2(hA[2]), xa3 = __half22float2(hA[3]);
        float dA = xa0.x * q0.x + xa0.y * q0.y + xa1.x * q0.z + xa1.y * q0.w
                 + xa2.x * q1.x + xa2.y * q1.y + xa3.x * q1.z + xa3.y * q1.w;
        #pragma unroll
        for (int off = 1; off <= 8; off <<= 1) dA += __shfl_xor(dA, off, 64);
        float attA = (dA + qo) * norm;
        a0.x += attA * xa0.x; a0.y += attA * xa0.y;
        a0.z += attA * xa1.x; a0.w += attA * xa1.y;
        a1.x += attA * xa2.x; a1.y += attA * xa2.y;
        a1.z += attA * xa3.x; a1.w += attA * xa3.y;
        asum += attA;
    }

    #pragma unroll
    for (int off = 16; off <= 32; off <<= 1) {
        a0.x += __shfl_xor(a0.x, off, 64);
        a0.y += __shfl_xor(a0.y, off, 64);
        a0.z += __shfl_xor(a0.z, off, 64);
        a0.w += __shfl_xor(a0.w, off, 64);
        a1.x += __shfl_xor(a1.x, off, 64);
        a1.y += __shfl_xor(a1.y, off, 64);
        a1.z += __shfl_xor(a1.z, off, 64);
        a1.w += __shfl_xor(a1.w, off, 64);
        asum += __shfl_xor(asum, off, 64);
    }

    __shared__ float s_part[4][128];
    __shared__ float s_as[4];
    if (lane < 16) {
        *(float4*)&s_part[wave][col8]     = a0;
        *(float4*)&s_part[wave][col8 + 4] = a1;
        if (lane == 0) s_as[wave] = asum;
    }
    __syncthreads();

    if (tid < 128) {
        float v = s_part[0][tid] + s_part[1][tid] + s_part[2][tid] + s_part[3][tid];
        agg[(size_t)p * 128 + tid] = v;
        if (tid == 0) att_sum[p] = s_as[0] + s_as[1] + s_as[2] + s_as[3];
    }
}

// ---------------------------------------------------------------------------
// K3 f32 fallback: half-wave x float4, 4 pairs in flight.
// ---------------------------------------------------------------------------
__global__ __launch_bounds__(256) void edge_agg_f32(
    const float* __restrict__ nodes, const float* __restrict__ qk,
    const float* __restrict__ qoff,
    const int* __restrict__ offsets, const int* __restrict__ ssrc,
    float* __restrict__ agg, float* __restrict__ att_sum)
{
    const float norm = 0.22360679774997896f;
    int p = blockIdx.x;
    int tid = threadIdx.x;
    int lane = tid & 63;
    int wave = tid >> 6;
    int half = lane >> 5;
    int colq = (lane & 31) * 4;

    const float4 q = *(const float4*)(qk + (size_t)p * 128 + colq);
    float qo = qoff[p];
    int beg = offsets[p], end = offsets[p + 1];
    int n = end - beg;
    int np = (n + 1) >> 1;
    int npfull = n >> 1;

    float4 a = {0.f, 0.f, 0.f, 0.f};
    float asum = 0.f;

    int pi = wave;
    for (; pi + 12 < npfull; pi += 16) {
        int e0 = beg + 2 * pi + half;
        int s0 = ssrc[e0];
        int s1 = ssrc[e0 + 8];
        int s2 = ssrc[e0 + 16];
        int s3 = ssrc[e0 + 24];
        float4 x0 = *(const float4*)(nodes + (size_t)s0 * 128 + colq);
        float4 x1 = *(const float4*)(nodes + (size_t)s1 * 128 + colq);
        float4 x2 = *(const float4*)(nodes + (size_t)s2 * 128 + colq);
        float4 x3 = *(const float4*)(nodes + (size_t)s3 * 128 + colq);
        float d0 = x0.x * q.x + x0.y * q.y + x0.z * q.z + x0.w * q.w;
        float d1 = x1.x * q.x + x1.y * q.y + x1.z * q.z + x1.w * q.w;
        float d2 = x2.x * q.x + x2.y * q.y + x2.z * q.z + x2.w * q.w;
        float d3 = x3.x * q.x + x3.y * q.y + x3.z * q.z + x3.w * q.w;
        #pragma unroll
        for (int off = 1; off <= 16; off <<= 1) {
            d0 += __shfl_xor(d0, off, 64);
            d1 += __shfl_xor(d1, off, 64);
            d2 += __shfl_xor(d2, off, 64);
            d3 += __shfl_xor(d3, off, 64);
        }
        float t0 = (d0 + qo) * norm;
        float t1 = (d1 + qo) * norm;
        float t2 = (d2 + qo) * norm;
        float t3 = (d3 + qo) * norm;
        a.x += t0 * x0.x + t1 * x1.x + t2 * x2.x + t3 * x3.x;
        a.y += t0 * x0.y + t1 * x1.y + t2 * x2.y + t3 * x3.y;
        a.z += t0 * x0.z + t1 * x1.z + t2 * x2.z + t3 * x3.z;
        a.w += t0 * x0.w + t1 * x1.w + t2 * x2.w + t3 * x3.w;
        asum += t0 + t1 + t2 + t3;
    }
    for (; pi < np; pi += 4) {
        int e0 = beg + 2 * pi;
        bool has1 = (e0 + 1 < end);
        int s0 = ssrc[e0];
        int s1 = has1 ? ssrc[e0 + 1] : s0;
        int s = half ? s1 : s0;
        float4 x = *(const float4*)(nodes + (size_t)s * 128 + colq);
        float d = x.x * q.x + x.y * q.y + x.z * q.z + x.w * q.w;
        #pragma unroll
        for (int off = 1; off <= 16; off <<= 1) d += __shfl_xor(d, off, 64);
        float att = (d + qo) * norm;
        if (half && !has1) att = 0.f;
        a.x += att * x.x; a.y += att * x.y; a.z += att * x.z; a.w += att * x.w;
        asum += att;
    }

    a.x += __shfl_xor(a.x, 32, 64);
    a.y += __shfl_xor(a.y, 32, 64);
    a.z += __shfl_xor(a.z, 32, 64);
    a.w += __shfl_xor(a.w, 32, 64);
    asum += __shfl_xor(asum, 32, 64);

    __shared__ float s_acc[4][128];
    __shared__ float s_as[4];
    if (lane < 32) {
        *(float4*)&s_acc[wave][colq] = a;
        if (lane == 0) s_as[wave] = asum;
    }
    __syncthreads();

    if (tid < 128) {
        float v = s_acc[0][tid] + s_acc[1][tid] + s_acc[2][tid] + s_acc[3][tid];
        agg[(size_t)p * 128 + tid] = v;
        if (tid == 0) att_sum[p] = s_as[0] + s_as[1] + s_as[2] + s_as[3];
    }
}

// ---------------------------------------------------------------------------
// K4: gate-interleaved GRU GEMM. 2500 blocks = 625 pgroups x 4 colgroups.
// Thread = (particle pl, column j); float4 acc = (r, z, i_n, h_n).
// Gates computed thread-locally; hnew written to global.
// ---------------------------------------------------------------------------
__global__ __launch_bounds__(256) void gru_gemm(
    const float* __restrict__ agg, const float* __restrict__ att_sum,
    const float* __restrict__ ph,
    const float* __restrict__ Wbig2, const float* __restrict__ binit,
    const float* __restrict__ bvec4, float* __restrict__ hnew)
{
    __shared__ float s_in[8][256];
    int t = threadIdx.x;
    int pg = blockIdx.x >> 2, cg = blockIdx.x & 3;
    int pbase = pg * 8;

    for (int f = t; f < 8 * 64; f += 256) {
        int pl = f >> 6, c4 = (f & 63) * 4;
        int p = pbase + pl;
        float4 v;
        if (c4 < 128) v = *(const float4*)(agg + (size_t)p * 128 + c4);
        else          v = *(const float4*)(ph + (size_t)p * 128 + (c4 - 128));
        *(float4*)&s_in[pl][c4] = v;
    }

    int pl = t >> 5, jq = t & 31;
    int j = cg * 32 + jq;
    float4 bi = *(const float4*)(binit + j * 4);
    float4 bv = *(const float4*)(bvec4 + j * 4);
    float asum = att_sum[pbase + pl];
    float4 acc;
    acc.x = bi.x + asum * bv.x;
    acc.y = bi.y + asum * bv.y;
    acc.z = bi.z + asum * bv.z;
    acc.w = bi.w + asum * bv.w;
    __syncthreads();

    const float* wp = Wbig2 + j * 4;
    #pragma unroll 4
    for (int k = 0; k < 256; k++) {
        float4 w = *(const float4*)(wp + k * 512);
        float x = s_in[pl][k];
        acc.x += x * w.x; acc.y += x * w.y;
        acc.z += x * w.z; acc.w += x * w.w;
    }

    float r = sigmoid_(acc.x);
    float z = sigmoid_(acc.y);
    float n = tanh_(acc.z + r * acc.w);
    float h = s_in[pl][128 + j];
    hnew[(size_t)(pbase + pl) * 128 + j] = (1.f - z) * n + z * h;
}

// ---------------------------------------------------------------------------
// K5: epilogue — LayerNorm + MLP + residual. 625 blocks x 8 particles.
// ---------------------------------------------------------------------------
__global__ __launch_bounds__(256) void epilogue_kernel(
    const float* __restrict__ hnew, const float* __restrict__ ph,
    const float* __restrict__ lng, const float* __restrict__ lnb,
    const float* __restrict__ W1, const float* __restrict__ b1,
    const float* __restrict__ W2, const float* __restrict__ b2,
    float* __restrict__ out)
{
    __shared__ float s_ln[8][128];
    __shared__ float s_hid[8][64];
    int t = threadIdx.x;
    int pbase = blockIdx.x * 8;
    int pl = t >> 5, jq = t & 31;
    int j4 = jq * 4;
    int p = pbase + pl;

    float4 hn = *(const float4*)(hnew + (size_t)p * 128 + j4);
    float sum = hn.x + hn.y + hn.z + hn.w;
    float sq  = hn.x * hn.x + hn.y * hn.y + hn.z * hn.z + hn.w * hn.w;
    #pragma unroll
    for (int off = 1; off <= 16; off <<= 1) {
        sum += __shfl_xor(sum, off, 64);
        sq  += __shfl_xor(sq, off, 64);
    }
    float mu = sum * (1.f / 128.f);
    float var = sq * (1.f / 128.f) - mu * mu;
    float rstd = rsqrtf(var + 1e-5f);
    {
        float4 g4 = *(const float4*)(lng + j4);
        float4 b4 = *(const float4*)(lnb + j4);
        float4 ln4;
        ln4.x = (hn.x - mu) * rstd * g4.x + b4.x;
        ln4.y = (hn.y - mu) * rstd * g4.y + b4.y;
        ln4.z = (hn.z - mu) * rstd * g4.z + b4.z;
        ln4.w = (hn.w - mu) * rstd * g4.w + b4.w;
        *(float4*)&s_ln[pl][j4] = ln4;
    }
    __syncthreads();

    for (int idx = t; idx < 8 * 64; idx += 256) {
        int pl2 = idx >> 6, u = idx & 63;
        float a0 = b1[u];
        #pragma unroll 4
        for (int k = 0; k < 128; k++) a0 += s_ln[pl2][k] * W1[k * 64 + u];
        s_hid[pl2][u] = fmaxf(a0, 0.f);
    }
    __syncthreads();

    float4 o = *(const float4*)(b2 + j4);
    #pragma unroll 4
    for (int u = 0; u < 64; u++) {
        float av = s_hid[pl][u];
        float4 w = *(const float4*)(W2 + u * 128 + j4);
        o.x += av * w.x; o.y += av * w.y; o.z += av * w.z; o.w += av * w.w;
    }
    float4 h4 = *(const float4*)(ph + (size_t)p * 128 + j4);
    float4 res;
    res.x = h4.x + o.x; res.y = h4.y + o.y;
    res.z = h4.z + o.z; res.w = h4.w + o.w;
    *(float4*)(out + (size_t)p * 128 + j4) = res;
}

// ---------------------------------------------------------------------------
extern "C" void kernel_launch(void* const* d_in, const int* in_sizes, int n_in,
                              void* d_out, int out_size, void* d_ws, size_t ws_size,
                              hipStream_t stream) {
    const float* nodes = (const float*)d_in[0];
    const float* ph    = (const float*)d_in[1];
    const float* gr    = (const float*)d_in[2];
    const int*   src   = (const int*)d_in[3];
    const int*   dst   = (const int*)d_in[4];
    const float* keyW  = (const float*)d_in[5];
    const float* keyb  = (const float*)d_in[6];
    const float* valW  = (const float*)d_in[7];
    const float* valb  = (const float*)d_in[8];
    const float* qW    = (const float*)d_in[9];
    const float* qb    = (const float*)d_in[10];
    const float* Wih   = (const float*)d_in[11];
    const float* Whh   = (const float*)d_in[12];
    const float* bih   = (const float*)d_in[13];
    const float* bhh   = (const float*)d_in[14];
    const float* lng   = (const float*)d_in[15];
    const float* lnb   = (const float*)d_in[16];
    const float* W1    = (const float*)d_in[17];
    const float* b1    = (const float*)d_in[18];
    const float* W2    = (const float*)d_in[19];
    const float* b2    = (const float*)d_in[20];
    float* out = (float*)d_out;

    // workspace layout
    float* ws_f    = (float*)d_ws;
    float* qk      = ws_f;                       // 640,000 (reused as hnew)
    float* qoff    = qk + 640000;                // 5,008
    float* agg     = qoff + 5008;                // 640,000
    float* att_sum = agg + 640000;               // 5,008
    float* Wbig2   = att_sum + 5008;             // 131,072
    float* binit   = Wbig2 + 131072;             // 512
    float* bvec4   = binit + 512;                // 512
    float* mkbuf   = bvec4 + 512;                // 392 (mk[256], ck, moff[260..388))
    float* M_      = mkbuf + 400;                // 32,768
    int*   totals  = (int*)(M_ + 32768);         // 5,008
    int*   offsets = totals + 5008;              // 5,008
    int*   bar     = offsets + 5008;             // 16
    int*   blockhist = bar + 16;                 // SORTB*5000 = 640,000
    int*   ssrc    = blockhist + (size_t)SORTB * N_PART;  // 1,000,000
    __half* nodes_h = (__half*)(ssrc + 1000000); // 12,800,000 halves

    size_t base_floats = 640000 + 5008 + 640000 + 5008 + 131072 + 512 + 512 + 400
                       + 32768 + 5008 + 5008 + 16 + (size_t)SORTB * N_PART + 1000000;
    size_t need_f16 = base_floats * 4 + (size_t)N_NODES * D_NODE * sizeof(__half);
    int use_f16 = (ws_size >= need_f16) ? 1 : 0;

    hipMemsetAsync(bar, 0, 16 * sizeof(int), stream);

    mega_setup<<<SETUP_GRID, 256, 0, stream>>>(
        nodes, nodes_h, use_f16, valW, Wih, Whh, valb, bih, bhh,
        qW, qb, keyW, keyb, Wbig2, binit, bvec4, M_, mkbuf);

    phase2_kernel<<<SORTB + 625, 256, 0, stream>>>(
        src, dst, ph, gr, M_, mkbuf, blockhist, totals, offsets, ssrc, qk, qoff, bar);

    if (use_f16) {
        edge_agg_f16<<<N_PART, 256, 0, stream>>>(nodes_h, qk, qoff, offsets, ssrc, agg, att_sum);
    } else {
        edge_agg_f32<<<N_PART, 256, 0, stream>>>(nodes, qk, qoff, offsets, ssrc, agg, att_sum);
    }

    // hnew aliases qk (qk is dead after edge_agg)
    gru_gemm<<<2500, 256, 0, stream>>>(agg, att_sum, ph, Wbig2, binit, bvec4, qk);

    epilogue_kernel<<<625, 256, 0, stream>>>(qk, ph, lng, lnb, W1, b1, W2, b2, out);
}

// Round 8
// 392.733 us; speedup vs baseline: 1.1140x; 1.1140x over previous
//
#include <hip/hip_runtime.h>
#include <hip/hip_fp16.h>
#include <math.h>

#define N_NODES 100000
#define N_PART  5000
#define N_EDGES 1000000
#define D_NODE  128
#define D_PART  128
#define D_ATT   20
#define SORTB   128   // counting-sort blocks
#define EPB     ((N_EDGES + SORTB - 1) / SORTB)

// mega_setup block ranges
#define CONV_END  12500
#define DOT_END   (CONV_END + 192)    // 49152 Wbig2-dot entries
#define COPY_END  (DOT_END + 256)     // 65536 Wbig2-copy entries
#define ZF_END    (COPY_END + 64)     // 16384 zero-fill (k<128, g=3)
#define BINIT_END (ZF_END + 2)        // 512 binit/bvec4 entries
#define MB_END    (BINIT_END + 128)   // 32768 M entries
#define MK_END    (MB_END + 1)        // mk/moff/ck
#define SETUP_GRID MK_END

__device__ __forceinline__ float sigmoid_(float x) { return 1.f / (1.f + __expf(-x)); }
__device__ __forceinline__ float tanh_(float x)    { return 1.f - 2.f / (__expf(2.f * x) + 1.f); }

// ---------------------------------------------------------------------------
// Mega setup (verified R7): all independent precompute in one launch.
// ---------------------------------------------------------------------------
__global__ __launch_bounds__(256) void mega_setup(
    const float* __restrict__ nodes, __half* __restrict__ nh, int use_f16,
    const float* __restrict__ valW, const float* __restrict__ Wih,
    const float* __restrict__ Whh, const float* __restrict__ valb,
    const float* __restrict__ bih, const float* __restrict__ bhh,
    const float* __restrict__ qW, const float* __restrict__ qb,
    const float* __restrict__ keyW, const float* __restrict__ keyb,
    float* __restrict__ Wbig2, float* __restrict__ binit,
    float* __restrict__ bvec4, float* __restrict__ M,
    float* __restrict__ mkbuf)
{
    int b = blockIdx.x;
    int t = threadIdx.x;

    if (b < CONV_END) {
        if (!use_f16) return;
        int i = b * 256 + t;
        float4 v = ((const float4*)nodes)[i];
        __half2 a = __floats2half2_rn(v.x, v.y);
        __half2 c = __floats2half2_rn(v.z, v.w);
        ((__half2*)nh)[i * 2]     = a;
        ((__half2*)nh)[i * 2 + 1] = c;
    } else if (b < DOT_END) {
        int idx = (b - CONV_END) * 256 + t;      // 49152 = 128k x 384c
        int k = idx / 384, c = idx % 384;
        const float* va = valW + (size_t)k * 128;
        const float* wb = Wih + (size_t)c * 128;
        float acc = 0.f;
        #pragma unroll 8
        for (int m = 0; m < 128; m++) acc += va[m] * wb[m];
        Wbig2[(size_t)k * 512 + (c & 127) * 4 + (c >> 7)] = acc;
    } else if (b < COPY_END) {
        int idx = (b - DOT_END) * 256 + t;       // 65536 = 128kp x 512
        int kp = idx >> 9, rem = idx & 511;
        int j = rem >> 2, g = rem & 3;
        float v = 0.f;
        if (g < 2)       v = Whh[(size_t)(g * 128 + j) * 128 + kp];
        else if (g == 3) v = Whh[(size_t)(256 + j) * 128 + kp];
        Wbig2[(size_t)(128 + kp) * 512 + rem] = v;
    } else if (b < ZF_END) {
        int idx = (b - COPY_END) * 256 + t;      // 16384 = 128k x 128j
        int k = idx >> 7, j = idx & 127;
        Wbig2[(size_t)k * 512 + j * 4 + 3] = 0.f;
    } else if (b < BINIT_END) {
        int idx = (b - ZF_END) * 256 + t;        // 512 = 128j x 4g
        int j = idx >> 2, g = idx & 3;
        float bi;
        if (g == 0)      bi = bih[j] + bhh[j];
        else if (g == 1) bi = bih[128 + j] + bhh[128 + j];
        else if (g == 2) bi = bih[256 + j];
        else             bi = bhh[256 + j];
        binit[idx] = bi;
        float bv = 0.f;
        if (g < 3) {
            const float* wr = Wih + (size_t)(g * 128 + j) * 128;
            #pragma unroll 8
            for (int m = 0; m < 128; m++) bv += valb[m] * wr[m];
        }
        bvec4[idx] = bv;
    } else if (b < MB_END) {
        int idx = (b - BINIT_END) * 256 + t;     // 32768 = 256k x 128j
        int k = idx >> 7, j = idx & 127;
        const float* qr = qW + k * 20;
        const float* kr = keyW + j * 20;
        float acc = 0.f;
        #pragma unroll
        for (int a = 0; a < D_ATT; a++) acc += qr[a] * kr[a];
        M[idx] = acc;
    } else {
        {
            float acc = 0.f;
            const float* qr = qW + t * 20;
            #pragma unroll
            for (int a = 0; a < D_ATT; a++) acc += qr[a] * keyb[a];
            mkbuf[t] = acc;
        }
        if (t < 128) {
            float acc = 0.f;
            const float* kr = keyW + t * 20;
            #pragma unroll
            for (int a = 0; a < D_ATT; a++) acc += qb[a] * kr[a];
            mkbuf[260 + t] = acc;
        }
        if (t == 0) {
            float acc = 0.f;
            #pragma unroll
            for (int a = 0; a < D_ATT; a++) acc += qb[a] * keyb[a];
            mkbuf[256] = acc;
        }
    }
}

// ---------------------------------------------------------------------------
// K2: blocks [0,128): per-block LDS histogram (independent of query part).
//     blocks [128,753): query GEMM qk = [ph|gr] @ M + moff; qoff.
// No inter-block dependencies — pure block-id dispatch fusion.
// ---------------------------------------------------------------------------
__global__ __launch_bounds__(256) void hist_query_kernel(
    const int* __restrict__ dst,
    const float* __restrict__ ph, const float* __restrict__ gr,
    const float* __restrict__ M, const float* __restrict__ mkbuf,
    int* __restrict__ blockhist,
    float* __restrict__ qk, float* __restrict__ qoff)
{
    __shared__ char smem[20000];
    int t = threadIdx.x;

    if (blockIdx.x < SORTB) {
        int b = blockIdx.x;
        int* h = (int*)smem;
        for (int i = t; i < N_PART; i += 256) h[i] = 0;
        __syncthreads();
        int beg = b * EPB, end = min(beg + EPB, N_EDGES);
        for (int e = beg + t; e < end; e += 256)
            atomicAdd(&h[dst[e]], 1);
        __syncthreads();
        for (int i = t; i < N_PART; i += 256)
            blockhist[(size_t)b * N_PART + i] = h[i];
    } else {
        float (*s_in)[256] = (float(*)[256])smem;
        int pbase = (blockIdx.x - SORTB) * 8;
        for (int f = t; f < 8 * 64; f += 256) {
            int pl = f >> 6, c4 = (f & 63) * 4;
            int p = pbase + pl;
            float4 v;
            if (c4 < 128) v = *(const float4*)(ph + (size_t)p * 128 + c4);
            else          v = *(const float4*)(gr + (size_t)p * 128 + (c4 - 128));
            *(float4*)&s_in[pl][c4] = v;
        }
        __syncthreads();
        int pl = t >> 5, jq = t & 31;
        int j4 = jq * 4;
        int p = pbase + pl;
        float4 acc = *(const float4*)(mkbuf + 260 + j4);   // moff
        #pragma unroll 4
        for (int k = 0; k < 256; k++) {
            float x = s_in[pl][k];
            float4 w = *(const float4*)(M + (size_t)k * 128 + j4);
            acc.x += x * w.x; acc.y += x * w.y; acc.z += x * w.z; acc.w += x * w.w;
        }
        *(float4*)(qk + (size_t)p * 128 + j4) = acc;
        if (jq == 0) {
            float o = mkbuf[256];  // ck
            for (int k = 0; k < 256; k++) o += s_in[pl][k] * mkbuf[k];
            qoff[p] = o;
        }
    }
}

// K2b: per-dst column scan over blocks
__global__ __launch_bounds__(256) void colscan_kernel(
    int* __restrict__ blockhist, int* __restrict__ totals)
{
    int i = blockIdx.x * 256 + threadIdx.x;
    if (i >= N_PART) return;
    int run = 0;
    for (int b = 0; b < SORTB; b++) {
        size_t idx = (size_t)b * N_PART + i;
        int v = blockhist[idx];
        blockhist[idx] = run;
        run += v;
    }
    totals[i] = run;
}

// K2c: exclusive scan of totals[5000] -> offsets[5001]
__global__ __launch_bounds__(256) void scan_kernel(
    const int* __restrict__ totals, int* __restrict__ offsets)
{
    __shared__ int ss[256];
    int t = threadIdx.x;
    const int CH = 20;
    int beg = t * CH;
    int end = min(beg + CH, N_PART);
    int lsum = 0;
    for (int i = beg; i < end; i++) lsum += totals[i];
    ss[t] = lsum;
    __syncthreads();
    for (int off = 1; off < 256; off <<= 1) {
        int v = (t >= off) ? ss[t - off] : 0;
        __syncthreads();
        ss[t] += v;
        __syncthreads();
    }
    int base = ss[t] - lsum;
    for (int i = beg; i < end; i++) {
        offsets[i] = base;
        base += totals[i];
    }
    if (t == 0) offsets[N_PART] = N_EDGES;
}

// K2d: scatter src into dst-sorted order using per-block LDS cursors
__global__ __launch_bounds__(256) void scatter_sorted_kernel(
    const int* __restrict__ src, const int* __restrict__ dst,
    const int* __restrict__ offsets, const int* __restrict__ blockhist,
    int* __restrict__ ssrc)
{
    __shared__ int cur[N_PART];
    int b = blockIdx.x;
    for (int i = threadIdx.x; i < N_PART; i += 256)
        cur[i] = offsets[i] + blockhist[(size_t)b * N_PART + i];
    __syncthreads();
    int beg = b * EPB, end = min(beg + EPB, N_EDGES);
    for (int e = beg + threadIdx.x; e < end; e += 256) {
        int d = dst[e];
        int pos = atomicAdd(&cur[d], 1);
        ssrc[pos] = src[e];
    }
}

// ---------------------------------------------------------------------------
// K3 fp16: quarter-wave (16 lanes x 16B = 8 halves) per edge.
// ---------------------------------------------------------------------------
__global__ __launch_bounds__(256) void edge_agg_f16(
    const __half* __restrict__ nh, const float* __restrict__ qk,
    const float* __restrict__ qoff,
    const int* __restrict__ offsets, const int* __restrict__ ssrc,
    float* __restrict__ agg, float* __restrict__ att_sum)
{
    const float norm = 0.22360679774997896f;  // 1/sqrt(20)
    int p = blockIdx.x;
    int tid = threadIdx.x;
    int lane = tid & 63;
    int wave = tid >> 6;
    int lane16 = lane & 15;
    int col8 = lane16 * 8;

    float4 q0 = *(const float4*)(qk + (size_t)p * 128 + col8);
    float4 q1 = *(const float4*)(qk + (size_t)p * 128 + col8 + 4);
    float qo = qoff[p];
    int beg = offsets[p];
    int n = offsets[p + 1] - beg;

    float4 a0 = {0.f, 0.f, 0.f, 0.f};
    float4 a1 = {0.f, 0.f, 0.f, 0.f};
    float asum = 0.f;

    int i = wave * 8 + (lane >> 4);
    for (; i + 4 < n; i += 32) {
        int sA = ssrc[beg + i];
        int sB = ssrc[beg + i + 4];
        float4 rawA = *(const float4*)(nh + (size_t)sA * 128 + col8);
        float4 rawB = *(const float4*)(nh + (size_t)sB * 128 + col8);
        const __half2* hA = (const __half2*)&rawA;
        const __half2* hB = (const __half2*)&rawB;
        float2 xa0 = __half22float2(hA[0]), xa1 = __half22float2(hA[1]);
        float2 xa2 = __half22float2(hA[2]), xa3 = __half22float2(hA[3]);
        float2 xb0 = __half22float2(hB[0]), xb1 = __half22float2(hB[1]);
        float2 xb2 = __half22float2(hB[2]), xb3 = __half22float2(hB[3]);
        float dA = xa0.x * q0.x + xa0.y * q0.y + xa1.x * q0.z + xa1.y * q0.w
                 + xa2.x * q1.x + xa2.y * q1.y + xa3.x * q1.z + xa3.y * q1.w;
        float dB = xb0.x * q0.x + xb0.y * q0.y + xb1.x * q0.z + xb1.y * q0.w
                 + xb2.x * q1.x + xb2.y * q1.y + xb3.x * q1.z + xb3.y * q1.w;
        #pragma unroll
        for (int off = 1; off <= 8; off <<= 1) {
            dA += __shfl_xor(dA, off, 64);
            dB += __shfl_xor(dB, off, 64);
        }
        float attA = (dA + qo) * norm;
        float attB = (dB + qo) * norm;
        a0.x += attA * xa0.x + attB * xb0.x;
        a0.y += attA * xa0.y + attB * xb0.y;
        a0.z += attA * xa1.x + attB * xb1.x;
        a0.w += attA * xa1.y + attB * xb1.y;
        a1.x += attA * xa2.x + attB * xb2.x;
        a1.y += attA * xa2.y + attB * xb2.y;
        a1.z += attA * xa3.x + attB * xb3.x;
        a1.w += attA * xa3.y + attB * xb3.y;
        asum += attA + attB;
    }
    if (i < n) {
        int sA = ssrc[beg + i];
        float4 rawA = *(const float4*)(nh + (size_t)sA * 128 + col8);
        const __half2* hA = (const __half2*)&rawA;
        float2 xa0 = __half22float2(hA[0]), xa1 = __half22float2(hA[1]);
        float2 xa2 = __half22float2(hA[2]), xa3 = __half22float2(hA[3]);
        float dA = xa0.x * q0.x + xa0.y * q0.y + xa1.x * q0.z + xa1.y * q0.w
                 + xa2.x * q1.x + xa2.y * q1.y + xa3.x * q1.z + xa3.y * q1.w;
        #pragma unroll
        for (int off = 1; off <= 8; off <<= 1) dA += __shfl_xor(dA, off, 64);
        float attA = (dA + qo) * norm;
        a0.x += attA * xa0.x; a0.y += attA * xa0.y;
        a0.z += attA * xa1.x; a0.w += attA * xa1.y;
        a1.x += attA * xa2.x; a1.y += attA * xa2.y;
        a1.z += attA * xa3.x; a1.w += attA * xa3.y;
        asum += attA;
    }

    #pragma unroll
    for (int off = 16; off <= 32; off <<= 1) {
        a0.x += __shfl_xor(a0.x, off, 64);
        a0.y += __shfl_xor(a0.y, off, 64);
        a0.z += __shfl_xor(a0.z, off, 64);
        a0.w += __shfl_xor(a0.w, off, 64);
        a1.x += __shfl_xor(a1.x, off, 64);
        a1.y += __shfl_xor(a1.y, off, 64);
        a1.z += __shfl_xor(a1.z, off, 64);
        a1.w += __shfl_xor(a1.w, off, 64);
        asum += __shfl_xor(asum, off, 64);
    }

    __shared__ float s_part[4][128];
    __shared__ float s_as[4];
    if (lane < 16) {
        *(float4*)&s_part[wave][col8]     = a0;
        *(float4*)&s_part[wave][col8 + 4] = a1;
        if (lane == 0) s_as[wave] = asum;
    }
    __syncthreads();

    if (tid < 128) {
        float v = s_part[0][tid] + s_part[1][tid] + s_part[2][tid] + s_part[3][tid];
        agg[(size_t)p * 128 + tid] = v;
        if (tid == 0) att_sum[p] = s_as[0] + s_as[1] + s_as[2] + s_as[3];
    }
}

// ---------------------------------------------------------------------------
// K3 f32 fallback
// ---------------------------------------------------------------------------
__global__ __launch_bounds__(256) void edge_agg_f32(
    const float* __restrict__ nodes, const float* __restrict__ qk,
    const float* __restrict__ qoff,
    const int* __restrict__ offsets, const int* __restrict__ ssrc,
    float* __restrict__ agg, float* __restrict__ att_sum)
{
    const float norm = 0.22360679774997896f;
    int p = blockIdx.x;
    int tid = threadIdx.x;
    int lane = tid & 63;
    int wave = tid >> 6;
    int half = lane >> 5;
    int colq = (lane & 31) * 4;

    const float4 q = *(const float4*)(qk + (size_t)p * 128 + colq);
    float qo = qoff[p];
    int beg = offsets[p], end = offsets[p + 1];
    int n = end - beg;
    int np = (n + 1) >> 1;
    int npfull = n >> 1;

    float4 a = {0.f, 0.f, 0.f, 0.f};
    float asum = 0.f;

    int pi = wave;
    for (; pi + 12 < npfull; pi += 16) {
        int e0 = beg + 2 * pi + half;
        int s0 = ssrc[e0];
        int s1 = ssrc[e0 + 8];
        int s2 = ssrc[e0 + 16];
        int s3 = ssrc[e0 + 24];
        float4 x0 = *(const float4*)(nodes + (size_t)s0 * 128 + colq);
        float4 x1 = *(const float4*)(nodes + (size_t)s1 * 128 + colq);
        float4 x2 = *(const float4*)(nodes + (size_t)s2 * 128 + colq);
        float4 x3 = *(const float4*)(nodes + (size_t)s3 * 128 + colq);
        float d0 = x0.x * q.x + x0.y * q.y + x0.z * q.z + x0.w * q.w;
        float d1 = x1.x * q.x + x1.y * q.y + x1.z * q.z + x1.w * q.w;
        float d2 = x2.x * q.x + x2.y * q.y + x2.z * q.z + x2.w * q.w;
        float d3 = x3.x * q.x + x3.y * q.y + x3.z * q.z + x3.w * q.w;
        #pragma unroll
        for (int off = 1; off <= 16; off <<= 1) {
            d0 += __shfl_xor(d0, off, 64);
            d1 += __shfl_xor(d1, off, 64);
            d2 += __shfl_xor(d2, off, 64);
            d3 += __shfl_xor(d3, off, 64);
        }
        float t0 = (d0 + qo) * norm;
        float t1 = (d1 + qo) * norm;
        float t2 = (d2 + qo) * norm;
        float t3 = (d3 + qo) * norm;
        a.x += t0 * x0.x + t1 * x1.x + t2 * x2.x + t3 * x3.x;
        a.y += t0 * x0.y + t1 * x1.y + t2 * x2.y + t3 * x3.y;
        a.z += t0 * x0.z + t1 * x1.z + t2 * x2.z + t3 * x3.z;
        a.w += t0 * x0.w + t1 * x1.w + t2 * x2.w + t3 * x3.w;
        asum += t0 + t1 + t2 + t3;
    }
    for (; pi < np; pi += 4) {
        int e0 = beg + 2 * pi;
        bool has1 = (e0 + 1 < end);
        int s0 = ssrc[e0];
        int s1 = has1 ? ssrc[e0 + 1] : s0;
        int s = half ? s1 : s0;
        float4 x = *(const float4*)(nodes + (size_t)s * 128 + colq);
        float d = x.x * q.x + x.y * q.y + x.z * q.z + x.w * q.w;
        #pragma unroll
        for (int off = 1; off <= 16; off <<= 1) d += __shfl_xor(d, off, 64);
        float att = (d + qo) * norm;
        if (half && !has1) att = 0.f;
        a.x += att * x.x; a.y += att * x.y; a.z += att * x.z; a.w += att * x.w;
        asum += att;
    }

    a.x += __shfl_xor(a.x, 32, 64);
    a.y += __shfl_xor(a.y, 32, 64);
    a.z += __shfl_xor(a.z, 32, 64);
    a.w += __shfl_xor(a.w, 32, 64);
    asum += __shfl_xor(asum, 32, 64);

    __shared__ float s_acc[4][128];
    __shared__ float s_as[4];
    if (lane < 32) {
        *(float4*)&s_acc[wave][colq] = a;
        if (lane == 0) s_as[wave] = asum;
    }
    __syncthreads();

    if (tid < 128) {
        float v = s_acc[0][tid] + s_acc[1][tid] + s_acc[2][tid] + s_acc[3][tid];
        agg[(size_t)p * 128 + tid] = v;
        if (tid == 0) att_sum[p] = s_as[0] + s_as[1] + s_as[2] + s_as[3];
    }
}

// ---------------------------------------------------------------------------
// K4: gate-interleaved GRU GEMM. 2500 blocks = 625 pgroups x 4 colgroups.
// ---------------------------------------------------------------------------
__global__ __launch_bounds__(256) void gru_gemm(
    const float* __restrict__ agg, const float* __restrict__ att_sum,
    const float* __restrict__ ph,
    const float* __restrict__ Wbig2, const float* __restrict__ binit,
    const float* __restrict__ bvec4, float* __restrict__ hnew)
{
    __shared__ float s_in[8][256];
    int t = threadIdx.x;
    int pg = blockIdx.x >> 2, cg = blockIdx.x & 3;
    int pbase = pg * 8;

    for (int f = t; f < 8 * 64; f += 256) {
        int pl = f >> 6, c4 = (f & 63) * 4;
        int p = pbase + pl;
        float4 v;
        if (c4 < 128) v = *(const float4*)(agg + (size_t)p * 128 + c4);
        else          v = *(const float4*)(ph + (size_t)p * 128 + (c4 - 128));
        *(float4*)&s_in[pl][c4] = v;
    }

    int pl = t >> 5, jq = t & 31;
    int j = cg * 32 + jq;
    float4 bi = *(const float4*)(binit + j * 4);
    float4 bv = *(const float4*)(bvec4 + j * 4);
    float asum = att_sum[pbase + pl];
    float4 acc;
    acc.x = bi.x + asum * bv.x;
    acc.y = bi.y + asum * bv.y;
    acc.z = bi.z + asum * bv.z;
    acc.w = bi.w + asum * bv.w;
    __syncthreads();

    const float* wp = Wbig2 + j * 4;
    #pragma unroll 4
    for (int k = 0; k < 256; k++) {
        float4 w = *(const float4*)(wp + k * 512);
        float x = s_in[pl][k];
        acc.x += x * w.x; acc.y += x * w.y;
        acc.z += x * w.z; acc.w += x * w.w;
    }

    float r = sigmoid_(acc.x);
    float z = sigmoid_(acc.y);
    float n = tanh_(acc.z + r * acc.w);
    float h = s_in[pl][128 + j];
    hnew[(size_t)(pbase + pl) * 128 + j] = (1.f - z) * n + z * h;
}

// ---------------------------------------------------------------------------
// K5: epilogue — LayerNorm + MLP + residual. 625 blocks x 8 particles.
// ---------------------------------------------------------------------------
__global__ __launch_bounds__(256) void epilogue_kernel(
    const float* __restrict__ hnew, const float* __restrict__ ph,
    const float* __restrict__ lng, const float* __restrict__ lnb,
    const float* __restrict__ W1, const float* __restrict__ b1,
    const float* __restrict__ W2, const float* __restrict__ b2,
    float* __restrict__ out)
{
    __shared__ float s_ln[8][128];
    __shared__ float s_hid[8][64];
    int t = threadIdx.x;
    int pbase = blockIdx.x * 8;
    int pl = t >> 5, jq = t & 31;
    int j4 = jq * 4;
    int p = pbase + pl;

    float4 hn = *(const float4*)(hnew + (size_t)p * 128 + j4);
    float sum = hn.x + hn.y + hn.z + hn.w;
    float sq  = hn.x * hn.x + hn.y * hn.y + hn.z * hn.z + hn.w * hn.w;
    #pragma unroll
    for (int off = 1; off <= 16; off <<= 1) {
        sum += __shfl_xor(sum, off, 64);
        sq  += __shfl_xor(sq, off, 64);
    }
    float mu = sum * (1.f / 128.f);
    float var = sq * (1.f / 128.f) - mu * mu;
    float rstd = rsqrtf(var + 1e-5f);
    {
        float4 g4 = *(const float4*)(lng + j4);
        float4 b4 = *(const float4*)(lnb + j4);
        float4 ln4;
        ln4.x = (hn.x - mu) * rstd * g4.x + b4.x;
        ln4.y = (hn.y - mu) * rstd * g4.y + b4.y;
        ln4.z = (hn.z - mu) * rstd * g4.z + b4.z;
        ln4.w = (hn.w - mu) * rstd * g4.w + b4.w;
        *(float4*)&s_ln[pl][j4] = ln4;
    }
    __syncthreads();

    for (int idx = t; idx < 8 * 64; idx += 256) {
        int pl2 = idx >> 6, u = idx & 63;
        float a0 = b1[u];
        #pragma unroll 4
        for (int k = 0; k < 128; k++) a0 += s_ln[pl2][k] * W1[k * 64 + u];
        s_hid[pl2][u] = fmaxf(a0, 0.f);
    }
    __syncthreads();

    float4 o = *(const float4*)(b2 + j4);
    #pragma unroll 4
    for (int u = 0; u < 64; u++) {
        float av = s_hid[pl][u];
        float4 w = *(const float4*)(W2 + u * 128 + j4);
        o.x += av * w.x; o.y += av * w.y; o.z += av * w.z; o.w += av * w.w;
    }
    float4 h4 = *(const float4*)(ph + (size_t)p * 128 + j4);
    float4 res;
    res.x = h4.x + o.x; res.y = h4.y + o.y;
    res.z = h4.z + o.z; res.w = h4.w + o.w;
    *(float4*)(out + (size_t)p * 128 + j4) = res;
}

// ---------------------------------------------------------------------------
extern "C" void kernel_launch(void* const* d_in, const int* in_sizes, int n_in,
                              void* d_out, int out_size, void* d_ws, size_t ws_size,
                              hipStream_t stream) {
    const float* nodes = (const float*)d_in[0];
    const float* ph    = (const float*)d_in[1];
    const float* gr    = (const float*)d_in[2];
    const int*   src   = (const int*)d_in[3];
    const int*   dst   = (const int*)d_in[4];
    const float* keyW  = (const float*)d_in[5];
    const float* keyb  = (const float*)d_in[6];
    const float* valW  = (const float*)d_in[7];
    const float* valb  = (const float*)d_in[8];
    const float* qW    = (const float*)d_in[9];
    const float* qb    = (const float*)d_in[10];
    const float* Wih   = (const float*)d_in[11];
    const float* Whh   = (const float*)d_in[12];
    const float* bih   = (const float*)d_in[13];
    const float* bhh   = (const float*)d_in[14];
    const float* lng   = (const float*)d_in[15];
    const float* lnb   = (const float*)d_in[16];
    const float* W1    = (const float*)d_in[17];
    const float* b1    = (const float*)d_in[18];
    const float* W2    = (const float*)d_in[19];
    const float* b2    = (const float*)d_in[20];
    float* out = (float*)d_out;

    // workspace layout
    float* ws_f    = (float*)d_ws;
    float* qk      = ws_f;                       // 640,000 (reused as hnew)
    float* qoff    = qk + 640000;                // 5,008
    float* agg     = qoff + 5008;                // 640,000
    float* att_sum = agg + 640000;               // 5,008
    float* Wbig2   = att_sum + 5008;             // 131,072
    float* binit   = Wbig2 + 131072;             // 512
    float* bvec4   = binit + 512;                // 512
    float* mkbuf   = bvec4 + 512;                // 400
    float* M_      = mkbuf + 400;                // 32,768
    int*   totals  = (int*)(M_ + 32768);         // 5,008
    int*   offsets = totals + 5008;              // 5,008
    int*   blockhist = offsets + 5008;           // SORTB*5000 = 640,000
    int*   ssrc    = blockhist + (size_t)SORTB * N_PART;  // 1,000,000
    __half* nodes_h = (__half*)(ssrc + 1000000); // 12,800,000 halves

    size_t base_floats = 640000 + 5008 + 640000 + 5008 + 131072 + 512 + 512 + 400
                       + 32768 + 5008 + 5008 + (size_t)SORTB * N_PART + 1000000;
    size_t need_f16 = base_floats * 4 + (size_t)N_NODES * D_NODE * sizeof(__half);
    int use_f16 = (ws_size >= need_f16) ? 1 : 0;

    mega_setup<<<SETUP_GRID, 256, 0, stream>>>(
        nodes, nodes_h, use_f16, valW, Wih, Whh, valb, bih, bhh,
        qW, qb, keyW, keyb, Wbig2, binit, bvec4, M_, mkbuf);

    hist_query_kernel<<<SORTB + 625, 256, 0, stream>>>(
        dst, ph, gr, M_, mkbuf, blockhist, qk, qoff);

    colscan_kernel<<<(N_PART + 255) / 256, 256, 0, stream>>>(blockhist, totals);
    scan_kernel<<<1, 256, 0, stream>>>(totals, offsets);
    scatter_sorted_kernel<<<SORTB, 256, 0, stream>>>(src, dst, offsets, blockhist, ssrc);

    if (use_f16) {
        edge_agg_f16<<<N_PART, 256, 0, stream>>>(nodes_h, qk, qoff, offsets, ssrc, agg, att_sum);
    } else {
        edge_agg_f32<<<N_PART, 256, 0, stream>>>(nodes, qk, qoff, offsets, ssrc, agg, att_sum);
    }

    // hnew aliases qk (qk is dead after edge_agg)
    gru_gemm<<<2500, 256, 0, stream>>>(agg, att_sum, ph, Wbig2, binit, bvec4, qk);

    epilogue_kernel<<<625, 256, 0, stream>>>(qk, ph, lng, lnb, W1, b1, W2, b2, out);
}

// Round 9
// 318.696 us; speedup vs baseline: 1.3728x; 1.2323x over previous
//
#include <hip/hip_runtime.h>
#include <hip/hip_fp16.h>
#include <math.h>

#define N_NODES 100000
#define N_PART  5000
#define N_EDGES 1000000
#define D_NODE  128
#define D_PART  128
#define D_ATT   20
#define SORTB   128   // counting-sort blocks
#define EPB     ((N_EDGES + SORTB - 1) / SORTB)

// mega_setup block ranges
#define CONV_END  12500
#define DOT_END   (CONV_END + 192)    // 49152 Wbig2-dot entries
#define COPY_END  (DOT_END + 256)     // 65536 Wbig2-copy entries
#define ZF_END    (COPY_END + 64)     // 16384 zero-fill (k<128, g=3)
#define BINIT_END (ZF_END + 2)        // 512 binit/bvec4 entries
#define MB_END    (BINIT_END + 128)   // 32768 M entries
#define MK_END    (MB_END + 1)        // mk/moff/ck
#define SETUP_GRID MK_END

__device__ __forceinline__ float sigmoid_(float x) { return 1.f / (1.f + __expf(-x)); }
__device__ __forceinline__ float tanh_(float x)    { return 1.f - 2.f / (__expf(2.f * x) + 1.f); }

// ---------------------------------------------------------------------------
// Mega setup: all independent precompute in one launch.
// ---------------------------------------------------------------------------
__global__ __launch_bounds__(256) void mega_setup(
    const float* __restrict__ nodes, __half* __restrict__ nh, int use_f16,
    const float* __restrict__ valW, const float* __restrict__ Wih,
    const float* __restrict__ Whh, const float* __restrict__ valb,
    const float* __restrict__ bih, const float* __restrict__ bhh,
    const float* __restrict__ qW, const float* __restrict__ qb,
    const float* __restrict__ keyW, const float* __restrict__ keyb,
    float* __restrict__ Wbig2, float* __restrict__ binit,
    float* __restrict__ bvec4, float* __restrict__ M,
    float* __restrict__ mkbuf)
{
    int b = blockIdx.x;
    int t = threadIdx.x;

    if (b < CONV_END) {
        if (!use_f16) return;
        int i = b * 256 + t;
        float4 v = ((const float4*)nodes)[i];
        __half2 a = __floats2half2_rn(v.x, v.y);
        __half2 c = __floats2half2_rn(v.z, v.w);
        ((__half2*)nh)[i * 2]     = a;
        ((__half2*)nh)[i * 2 + 1] = c;
    } else if (b < DOT_END) {
        int idx = (b - CONV_END) * 256 + t;      // 49152 = 128k x 384c
        int k = idx / 384, c = idx % 384;
        const float* va = valW + (size_t)k * 128;
        const float* wb = Wih + (size_t)c * 128;
        float acc = 0.f;
        #pragma unroll 8
        for (int m = 0; m < 128; m++) acc += va[m] * wb[m];
        Wbig2[(size_t)k * 512 + (c & 127) * 4 + (c >> 7)] = acc;
    } else if (b < COPY_END) {
        int idx = (b - DOT_END) * 256 + t;       // 65536 = 128kp x 512
        int kp = idx >> 9, rem = idx & 511;
        int j = rem >> 2, g = rem & 3;
        float v = 0.f;
        if (g < 2)       v = Whh[(size_t)(g * 128 + j) * 128 + kp];
        else if (g == 3) v = Whh[(size_t)(256 + j) * 128 + kp];
        Wbig2[(size_t)(128 + kp) * 512 + rem] = v;
    } else if (b < ZF_END) {
        int idx = (b - COPY_END) * 256 + t;      // 16384 = 128k x 128j
        int k = idx >> 7, j = idx & 127;
        Wbig2[(size_t)k * 512 + j * 4 + 3] = 0.f;
    } else if (b < BINIT_END) {
        int idx = (b - ZF_END) * 256 + t;        // 512 = 128j x 4g
        int j = idx >> 2, g = idx & 3;
        float bi;
        if (g == 0)      bi = bih[j] + bhh[j];
        else if (g == 1) bi = bih[128 + j] + bhh[128 + j];
        else if (g == 2) bi = bih[256 + j];
        else             bi = bhh[256 + j];
        binit[idx] = bi;
        float bv = 0.f;
        if (g < 3) {
            const float* wr = Wih + (size_t)(g * 128 + j) * 128;
            #pragma unroll 8
            for (int m = 0; m < 128; m++) bv += valb[m] * wr[m];
        }
        bvec4[idx] = bv;
    } else if (b < MB_END) {
        int idx = (b - BINIT_END) * 256 + t;     // 32768 = 256k x 128j
        int k = idx >> 7, j = idx & 127;
        const float* qr = qW + k * 20;
        const float* kr = keyW + j * 20;
        float acc = 0.f;
        #pragma unroll
        for (int a = 0; a < D_ATT; a++) acc += qr[a] * kr[a];
        M[idx] = acc;
    } else {
        {
            float acc = 0.f;
            const float* qr = qW + t * 20;
            #pragma unroll
            for (int a = 0; a < D_ATT; a++) acc += qr[a] * keyb[a];
            mkbuf[t] = acc;
        }
        if (t < 128) {
            float acc = 0.f;
            const float* kr = keyW + t * 20;
            #pragma unroll
            for (int a = 0; a < D_ATT; a++) acc += qb[a] * kr[a];
            mkbuf[260 + t] = acc;
        }
        if (t == 0) {
            float acc = 0.f;
            #pragma unroll
            for (int a = 0; a < D_ATT; a++) acc += qb[a] * keyb[a];
            mkbuf[256] = acc;
        }
    }
}

// ---------------------------------------------------------------------------
// K2: blocks [0,128): per-block LDS histogram; blocks [128,753): query GEMM.
// ---------------------------------------------------------------------------
__global__ __launch_bounds__(256) void hist_query_kernel(
    const int* __restrict__ dst,
    const float* __restrict__ ph, const float* __restrict__ gr,
    const float* __restrict__ M, const float* __restrict__ mkbuf,
    int* __restrict__ blockhist,
    float* __restrict__ qk, float* __restrict__ qoff)
{
    __shared__ char smem[20000];
    int t = threadIdx.x;

    if (blockIdx.x < SORTB) {
        int b = blockIdx.x;
        int* h = (int*)smem;
        for (int i = t; i < N_PART; i += 256) h[i] = 0;
        __syncthreads();
        int beg = b * EPB, end = min(beg + EPB, N_EDGES);
        for (int e = beg + t; e < end; e += 256)
            atomicAdd(&h[dst[e]], 1);
        __syncthreads();
        for (int i = t; i < N_PART; i += 256)
            blockhist[(size_t)b * N_PART + i] = h[i];
    } else {
        float (*s_in)[256] = (float(*)[256])smem;
        int pbase = (blockIdx.x - SORTB) * 8;
        for (int f = t; f < 8 * 64; f += 256) {
            int pl = f >> 6, c4 = (f & 63) * 4;
            int p = pbase + pl;
            float4 v;
            if (c4 < 128) v = *(const float4*)(ph + (size_t)p * 128 + c4);
            else          v = *(const float4*)(gr + (size_t)p * 128 + (c4 - 128));
            *(float4*)&s_in[pl][c4] = v;
        }
        __syncthreads();
        int pl = t >> 5, jq = t & 31;
        int j4 = jq * 4;
        int p = pbase + pl;
        float4 acc = *(const float4*)(mkbuf + 260 + j4);   // moff
        #pragma unroll 4
        for (int k = 0; k < 256; k++) {
            float x = s_in[pl][k];
            float4 w = *(const float4*)(M + (size_t)k * 128 + j4);
            acc.x += x * w.x; acc.y += x * w.y; acc.z += x * w.z; acc.w += x * w.w;
        }
        *(float4*)(qk + (size_t)p * 128 + j4) = acc;
        if (jq == 0) {
            float o = mkbuf[256];  // ck
            for (int k = 0; k < 256; k++) o += s_in[pl][k] * mkbuf[k];
            qoff[p] = o;
        }
    }
}

// K2b: per-dst column scan over blocks
__global__ __launch_bounds__(256) void colscan_kernel(
    int* __restrict__ blockhist, int* __restrict__ totals)
{
    int i = blockIdx.x * 256 + threadIdx.x;
    if (i >= N_PART) return;
    int run = 0;
    for (int b = 0; b < SORTB; b++) {
        size_t idx = (size_t)b * N_PART + i;
        int v = blockhist[idx];
        blockhist[idx] = run;
        run += v;
    }
    totals[i] = run;
}

// K2c: exclusive scan of totals[5000] -> offsets[5001]
__global__ __launch_bounds__(256) void scan_kernel(
    const int* __restrict__ totals, int* __restrict__ offsets)
{
    __shared__ int ss[256];
    int t = threadIdx.x;
    const int CH = 20;
    int beg = t * CH;
    int end = min(beg + CH, N_PART);
    int lsum = 0;
    for (int i = beg; i < end; i++) lsum += totals[i];
    ss[t] = lsum;
    __syncthreads();
    for (int off = 1; off < 256; off <<= 1) {
        int v = (t >= off) ? ss[t - off] : 0;
        __syncthreads();
        ss[t] += v;
        __syncthreads();
    }
    int base = ss[t] - lsum;
    for (int i = beg; i < end; i++) {
        offsets[i] = base;
        base += totals[i];
    }
    if (t == 0) offsets[N_PART] = N_EDGES;
}

// K2d: scatter src into dst-sorted order using per-block LDS cursors
__global__ __launch_bounds__(256) void scatter_sorted_kernel(
    const int* __restrict__ src, const int* __restrict__ dst,
    const int* __restrict__ offsets, const int* __restrict__ blockhist,
    int* __restrict__ ssrc)
{
    __shared__ int cur[N_PART];
    int b = blockIdx.x;
    for (int i = threadIdx.x; i < N_PART; i += 256)
        cur[i] = offsets[i] + blockhist[(size_t)b * N_PART + i];
    __syncthreads();
    int beg = b * EPB, end = min(beg + EPB, N_EDGES);
    for (int e = beg + threadIdx.x; e < end; e += 256) {
        int d = dst[e];
        int pos = atomicAdd(&cur[d], 1);
        ssrc[pos] = src[e];
    }
}

// ---------------------------------------------------------------------------
// K3 fp16: quarter-wave (16 lanes x 16B = 8 halves) per edge.
// ---------------------------------------------------------------------------
__global__ __launch_bounds__(256) void edge_agg_f16(
    const __half* __restrict__ nh, const float* __restrict__ qk,
    const float* __restrict__ qoff,
    const int* __restrict__ offsets, const int* __restrict__ ssrc,
    float* __restrict__ agg, float* __restrict__ att_sum)
{
    const float norm = 0.22360679774997896f;  // 1/sqrt(20)
    int p = blockIdx.x;
    int tid = threadIdx.x;
    int lane = tid & 63;
    int wave = tid >> 6;
    int lane16 = lane & 15;
    int col8 = lane16 * 8;

    float4 q0 = *(const float4*)(qk + (size_t)p * 128 + col8);
    float4 q1 = *(const float4*)(qk + (size_t)p * 128 + col8 + 4);
    float qo = qoff[p];
    int beg = offsets[p];
    int n = offsets[p + 1] - beg;

    float4 a0 = {0.f, 0.f, 0.f, 0.f};
    float4 a1 = {0.f, 0.f, 0.f, 0.f};
    float asum = 0.f;

    int i = wave * 8 + (lane >> 4);
    for (; i + 4 < n; i += 32) {
        int sA = ssrc[beg + i];
        int sB = ssrc[beg + i + 4];
        float4 rawA = *(const float4*)(nh + (size_t)sA * 128 + col8);
        float4 rawB = *(const float4*)(nh + (size_t)sB * 128 + col8);
        const __half2* hA = (const __half2*)&rawA;
        const __half2* hB = (const __half2*)&rawB;
        float2 xa0 = __half22float2(hA[0]), xa1 = __half22float2(hA[1]);
        float2 xa2 = __half22float2(hA[2]), xa3 = __half22float2(hA[3]);
        float2 xb0 = __half22float2(hB[0]), xb1 = __half22float2(hB[1]);
        float2 xb2 = __half22float2(hB[2]), xb3 = __half22float2(hB[3]);
        float dA = xa0.x * q0.x + xa0.y * q0.y + xa1.x * q0.z + xa1.y * q0.w
                 + xa2.x * q1.x + xa2.y * q1.y + xa3.x * q1.z + xa3.y * q1.w;
        float dB = xb0.x * q0.x + xb0.y * q0.y + xb1.x * q0.z + xb1.y * q0.w
                 + xb2.x * q1.x + xb2.y * q1.y + xb3.x * q1.z + xb3.y * q1.w;
        #pragma unroll
        for (int off = 1; off <= 8; off <<= 1) {
            dA += __shfl_xor(dA, off, 64);
            dB += __shfl_xor(dB, off, 64);
        }
        float attA = (dA + qo) * norm;
        float attB = (dB + qo) * norm;
        a0.x += attA * xa0.x + attB * xb0.x;
        a0.y += attA * xa0.y + attB * xb0.y;
        a0.z += attA * xa1.x + attB * xb1.x;
        a0.w += attA * xa1.y + attB * xb1.y;
        a1.x += attA * xa2.x + attB * xb2.x;
        a1.y += attA * xa2.y + attB * xb2.y;
        a1.z += attA * xa3.x + attB * xb3.x;
        a1.w += attA * xa3.y + attB * xb3.y;
        asum += attA + attB;
    }
    if (i < n) {
        int sA = ssrc[beg + i];
        float4 rawA = *(const float4*)(nh + (size_t)sA * 128 + col8);
        const __half2* hA = (const __half2*)&rawA;
        float2 xa0 = __half22float2(hA[0]), xa1 = __half22float2(hA[1]);
        float2 xa2 = __half22float2(hA[2]), xa3 = __half22float2(hA[3]);
        float dA = xa0.x * q0.x + xa0.y * q0.y + xa1.x * q0.z + xa1.y * q0.w
                 + xa2.x * q1.x + xa2.y * q1.y + xa3.x * q1.z + xa3.y * q1.w;
        #pragma unroll
        for (int off = 1; off <= 8; off <<= 1) dA += __shfl_xor(dA, off, 64);
        float attA = (dA + qo) * norm;
        a0.x += attA * xa0.x; a0.y += attA * xa0.y;
        a0.z += attA * xa1.x; a0.w += attA * xa1.y;
        a1.x += attA * xa2.x; a1.y += attA * xa2.y;
        a1.z += attA * xa3.x; a1.w += attA * xa3.y;
        asum += attA;
    }

    #pragma unroll
    for (int off = 16; off <= 32; off <<= 1) {
        a0.x += __shfl_xor(a0.x, off, 64);
        a0.y += __shfl_xor(a0.y, off, 64);
        a0.z += __shfl_xor(a0.z, off, 64);
        a0.w += __shfl_xor(a0.w, off, 64);
        a1.x += __shfl_xor(a1.x, off, 64);
        a1.y += __shfl_xor(a1.y, off, 64);
        a1.z += __shfl_xor(a1.z, off, 64);
        a1.w += __shfl_xor(a1.w, off, 64);
        asum += __shfl_xor(asum, off, 64);
    }

    __shared__ float s_part[4][128];
    __shared__ float s_as[4];
    if (lane < 16) {
        *(float4*)&s_part[wave][col8]     = a0;
        *(float4*)&s_part[wave][col8 + 4] = a1;
        if (lane == 0) s_as[wave] = asum;
    }
    __syncthreads();

    if (tid < 128) {
        float v = s_part[0][tid] + s_part[1][tid] + s_part[2][tid] + s_part[3][tid];
        agg[(size_t)p * 128 + tid] = v;
        if (tid == 0) att_sum[p] = s_as[0] + s_as[1] + s_as[2] + s_as[3];
    }
}

// ---------------------------------------------------------------------------
// K3 f32 fallback
// ---------------------------------------------------------------------------
__global__ __launch_bounds__(256) void edge_agg_f32(
    const float* __restrict__ nodes, const float* __restrict__ qk,
    const float* __restrict__ qoff,
    const int* __restrict__ offsets, const int* __restrict__ ssrc,
    float* __restrict__ agg, float* __restrict__ att_sum)
{
    const float norm = 0.22360679774997896f;
    int p = blockIdx.x;
    int tid = threadIdx.x;
    int lane = tid & 63;
    int wave = tid >> 6;
    int half = lane >> 5;
    int colq = (lane & 31) * 4;

    const float4 q = *(const float4*)(qk + (size_t)p * 128 + colq);
    float qo = qoff[p];
    int beg = offsets[p], end = offsets[p + 1];
    int n = end - beg;
    int np = (n + 1) >> 1;
    int npfull = n >> 1;

    float4 a = {0.f, 0.f, 0.f, 0.f};
    float asum = 0.f;

    int pi = wave;
    for (; pi + 12 < npfull; pi += 16) {
        int e0 = beg + 2 * pi + half;
        int s0 = ssrc[e0];
        int s1 = ssrc[e0 + 8];
        int s2 = ssrc[e0 + 16];
        int s3 = ssrc[e0 + 24];
        float4 x0 = *(const float4*)(nodes + (size_t)s0 * 128 + colq);
        float4 x1 = *(const float4*)(nodes + (size_t)s1 * 128 + colq);
        float4 x2 = *(const float4*)(nodes + (size_t)s2 * 128 + colq);
        float4 x3 = *(const float4*)(nodes + (size_t)s3 * 128 + colq);
        float d0 = x0.x * q.x + x0.y * q.y + x0.z * q.z + x0.w * q.w;
        float d1 = x1.x * q.x + x1.y * q.y + x1.z * q.z + x1.w * q.w;
        float d2 = x2.x * q.x + x2.y * q.y + x2.z * q.z + x2.w * q.w;
        float d3 = x3.x * q.x + x3.y * q.y + x3.z * q.z + x3.w * q.w;
        #pragma unroll
        for (int off = 1; off <= 16; off <<= 1) {
            d0 += __shfl_xor(d0, off, 64);
            d1 += __shfl_xor(d1, off, 64);
            d2 += __shfl_xor(d2, off, 64);
            d3 += __shfl_xor(d3, off, 64);
        }
        float t0 = (d0 + qo) * norm;
        float t1 = (d1 + qo) * norm;
        float t2 = (d2 + qo) * norm;
        float t3 = (d3 + qo) * norm;
        a.x += t0 * x0.x + t1 * x1.x + t2 * x2.x + t3 * x3.x;
        a.y += t0 * x0.y + t1 * x1.y + t2 * x2.y + t3 * x3.y;
        a.z += t0 * x0.z + t1 * x1.z + t2 * x2.z + t3 * x3.z;
        a.w += t0 * x0.w + t1 * x1.w + t2 * x2.w + t3 * x3.w;
        asum += t0 + t1 + t2 + t3;
    }
    for (; pi < np; pi += 4) {
        int e0 = beg + 2 * pi;
        bool has1 = (e0 + 1 < end);
        int s0 = ssrc[e0];
        int s1 = has1 ? ssrc[e0 + 1] : s0;
        int s = half ? s1 : s0;
        float4 x = *(const float4*)(nodes + (size_t)s * 128 + colq);
        float d = x.x * q.x + x.y * q.y + x.z * q.z + x.w * q.w;
        #pragma unroll
        for (int off = 1; off <= 16; off <<= 1) d += __shfl_xor(d, off, 64);
        float att = (d + qo) * norm;
        if (half && !has1) att = 0.f;
        a.x += att * x.x; a.y += att * x.y; a.z += att * x.z; a.w += att * x.w;
        asum += att;
    }

    a.x += __shfl_xor(a.x, 32, 64);
    a.y += __shfl_xor(a.y, 32, 64);
    a.z += __shfl_xor(a.z, 32, 64);
    a.w += __shfl_xor(a.w, 32, 64);
    asum += __shfl_xor(asum, 32, 64);

    __shared__ float s_acc[4][128];
    __shared__ float s_as[4];
    if (lane < 32) {
        *(float4*)&s_acc[wave][colq] = a;
        if (lane == 0) s_as[wave] = asum;
    }
    __syncthreads();

    if (tid < 128) {
        float v = s_acc[0][tid] + s_acc[1][tid] + s_acc[2][tid] + s_acc[3][tid];
        agg[(size_t)p * 128 + tid] = v;
        if (tid == 0) att_sum[p] = s_as[0] + s_as[1] + s_as[2] + s_as[3];
    }
}

// ---------------------------------------------------------------------------
// K4 v2: gate-interleaved GRU GEMM with 4 particles per thread.
// Grid = 157 pgroups x 4 cgroups = 628 blocks; block = 32 particles x 32 cols.
// Thread (tp,jq): 4 float4 accs -> 16 FMAs per 16B weight load (VALU-bound).
// ---------------------------------------------------------------------------
__global__ __launch_bounds__(256) void gru_gemm_v2(
    const float* __restrict__ agg, const float* __restrict__ att_sum,
    const float* __restrict__ ph,
    const float* __restrict__ Wbig2, const float* __restrict__ binit,
    const float* __restrict__ bvec4, float* __restrict__ hnew)
{
    __shared__ float s_in[32][256];   // 32 KB: [agg | h] for 32 particles
    int t = threadIdx.x;
    int pg = blockIdx.x >> 2, cg = blockIdx.x & 3;
    int pbase = pg * 32;

    for (int f = t; f < 32 * 64; f += 256) {
        int pl = f >> 6, c4 = (f & 63) * 4;
        int p = min(pbase + pl, N_PART - 1);
        float4 v;
        if (c4 < 128) v = *(const float4*)(agg + (size_t)p * 128 + c4);
        else          v = *(const float4*)(ph + (size_t)p * 128 + (c4 - 128));
        *(float4*)&s_in[pl][c4] = v;
    }

    int tp = t >> 5, jq = t & 31;
    int j = cg * 32 + jq;
    int p0 = pbase + tp * 4;
    float4 bi = *(const float4*)(binit + j * 4);
    float4 bv = *(const float4*)(bvec4 + j * 4);
    float as0 = att_sum[min(p0 + 0, N_PART - 1)];
    float as1 = att_sum[min(p0 + 1, N_PART - 1)];
    float as2 = att_sum[min(p0 + 2, N_PART - 1)];
    float as3 = att_sum[min(p0 + 3, N_PART - 1)];
    float4 acc0, acc1, acc2, acc3;
    acc0.x = bi.x + as0 * bv.x; acc0.y = bi.y + as0 * bv.y;
    acc0.z = bi.z + as0 * bv.z; acc0.w = bi.w + as0 * bv.w;
    acc1.x = bi.x + as1 * bv.x; acc1.y = bi.y + as1 * bv.y;
    acc1.z = bi.z + as1 * bv.z; acc1.w = bi.w + as1 * bv.w;
    acc2.x = bi.x + as2 * bv.x; acc2.y = bi.y + as2 * bv.y;
    acc2.z = bi.z + as2 * bv.z; acc2.w = bi.w + as2 * bv.w;
    acc3.x = bi.x + as3 * bv.x; acc3.y = bi.y + as3 * bv.y;
    acc3.z = bi.z + as3 * bv.z; acc3.w = bi.w + as3 * bv.w;
    __syncthreads();

    int lp = tp * 4;
    const float* wp = Wbig2 + j * 4;
    #pragma unroll 4
    for (int k = 0; k < 256; k++) {
        float4 w = *(const float4*)(wp + (size_t)k * 512);
        float x0 = s_in[lp + 0][k];
        float x1 = s_in[lp + 1][k];
        float x2 = s_in[lp + 2][k];
        float x3 = s_in[lp + 3][k];
        acc0.x += x0 * w.x; acc0.y += x0 * w.y; acc0.z += x0 * w.z; acc0.w += x0 * w.w;
        acc1.x += x1 * w.x; acc1.y += x1 * w.y; acc1.z += x1 * w.z; acc1.w += x1 * w.w;
        acc2.x += x2 * w.x; acc2.y += x2 * w.y; acc2.z += x2 * w.z; acc2.w += x2 * w.w;
        acc3.x += x3 * w.x; acc3.y += x3 * w.y; acc3.z += x3 * w.z; acc3.w += x3 * w.w;
    }

    #pragma unroll
    for (int i = 0; i < 4; i++) {
        float4 acc = (i == 0) ? acc0 : (i == 1) ? acc1 : (i == 2) ? acc2 : acc3;
        int p = p0 + i;
        float r = sigmoid_(acc.x);
        float z = sigmoid_(acc.y);
        float n = tanh_(acc.z + r * acc.w);
        float h = s_in[lp + i][128 + j];
        if (p < N_PART)
            hnew[(size_t)p * 128 + j] = (1.f - z) * n + z * h;
    }
}

// ---------------------------------------------------------------------------
// K5: epilogue — LayerNorm + MLP + residual. 625 blocks x 8 particles.
// ---------------------------------------------------------------------------
__global__ __launch_bounds__(256) void epilogue_kernel(
    const float* __restrict__ hnew, const float* __restrict__ ph,
    const float* __restrict__ lng, const float* __restrict__ lnb,
    const float* __restrict__ W1, const float* __restrict__ b1,
    const float* __restrict__ W2, const float* __restrict__ b2,
    float* __restrict__ out)
{
    __shared__ float s_ln[8][128];
    __shared__ float s_hid[8][64];
    int t = threadIdx.x;
    int pbase = blockIdx.x * 8;
    int pl = t >> 5, jq = t & 31;
    int j4 = jq * 4;
    int p = pbase + pl;

    float4 hn = *(const float4*)(hnew + (size_t)p * 128 + j4);
    float sum = hn.x + hn.y + hn.z + hn.w;
    float sq  = hn.x * hn.x + hn.y * hn.y + hn.z * hn.z + hn.w * hn.w;
    #pragma unroll
    for (int off = 1; off <= 16; off <<= 1) {
        sum += __shfl_xor(sum, off, 64);
        sq  += __shfl_xor(sq, off, 64);
    }
    float mu = sum * (1.f / 128.f);
    float var = sq * (1.f / 128.f) - mu * mu;
    float rstd = rsqrtf(var + 1e-5f);
    {
        float4 g4 = *(const float4*)(lng + j4);
        float4 b4 = *(const float4*)(lnb + j4);
        float4 ln4;
        ln4.x = (hn.x - mu) * rstd * g4.x + b4.x;
        ln4.y = (hn.y - mu) * rstd * g4.y + b4.y;
        ln4.z = (hn.z - mu) * rstd * g4.z + b4.z;
        ln4.w = (hn.w - mu) * rstd * g4.w + b4.w;
        *(float4*)&s_ln[pl][j4] = ln4;
    }
    __syncthreads();

    for (int idx = t; idx < 8 * 64; idx += 256) {
        int pl2 = idx >> 6, u = idx & 63;
        float a0 = b1[u];
        #pragma unroll 4
        for (int k = 0; k < 128; k++) a0 += s_ln[pl2][k] * W1[k * 64 + u];
        s_hid[pl2][u] = fmaxf(a0, 0.f);
    }
    __syncthreads();

    float4 o = *(const float4*)(b2 + j4);
    #pragma unroll 4
    for (int u = 0; u < 64; u++) {
        float av = s_hid[pl][u];
        float4 w = *(const float4*)(W2 + u * 128 + j4);
        o.x += av * w.x; o.y += av * w.y; o.z += av * w.z; o.w += av * w.w;
    }
    float4 h4 = *(const float4*)(ph + (size_t)p * 128 + j4);
    float4 res;
    res.x = h4.x + o.x; res.y = h4.y + o.y;
    res.z = h4.z + o.z; res.w = h4.w + o.w;
    *(float4*)(out + (size_t)p * 128 + j4) = res;
}

// ---------------------------------------------------------------------------
extern "C" void kernel_launch(void* const* d_in, const int* in_sizes, int n_in,
                              void* d_out, int out_size, void* d_ws, size_t ws_size,
                              hipStream_t stream) {
    const float* nodes = (const float*)d_in[0];
    const float* ph    = (const float*)d_in[1];
    const float* gr    = (const float*)d_in[2];
    const int*   src   = (const int*)d_in[3];
    const int*   dst   = (const int*)d_in[4];
    const float* keyW  = (const float*)d_in[5];
    const float* keyb  = (const float*)d_in[6];
    const float* valW  = (const float*)d_in[7];
    const float* valb  = (const float*)d_in[8];
    const float* qW    = (const float*)d_in[9];
    const float* qb    = (const float*)d_in[10];
    const float* Wih   = (const float*)d_in[11];
    const float* Whh   = (const float*)d_in[12];
    const float* bih   = (const float*)d_in[13];
    const float* bhh   = (const float*)d_in[14];
    const float* lng   = (const float*)d_in[15];
    const float* lnb   = (const float*)d_in[16];
    const float* W1    = (const float*)d_in[17];
    const float* b1    = (const float*)d_in[18];
    const float* W2    = (const float*)d_in[19];
    const float* b2    = (const float*)d_in[20];
    float* out = (float*)d_out;

    // workspace layout
    float* ws_f    = (float*)d_ws;
    float* qk      = ws_f;                       // 640,000 (reused as hnew)
    float* qoff    = qk + 640000;                // 5,008
    float* agg     = qoff + 5008;                // 640,000
    float* att_sum = agg + 640000;               // 5,008
    float* Wbig2   = att_sum + 5008;             // 131,072
    float* binit   = Wbig2 + 131072;             // 512
    float* bvec4   = binit + 512;                // 512
    float* mkbuf   = bvec4 + 512;                // 400
    float* M_      = mkbuf + 400;                // 32,768
    int*   totals  = (int*)(M_ + 32768);         // 5,008
    int*   offsets = totals + 5008;              // 5,008
    int*   blockhist = offsets + 5008;           // SORTB*5000 = 640,000
    int*   ssrc    = blockhist + (size_t)SORTB * N_PART;  // 1,000,000
    __half* nodes_h = (__half*)(ssrc + 1000000); // 12,800,000 halves

    size_t base_floats = 640000 + 5008 + 640000 + 5008 + 131072 + 512 + 512 + 400
                       + 32768 + 5008 + 5008 + (size_t)SORTB * N_PART + 1000000;
    size_t need_f16 = base_floats * 4 + (size_t)N_NODES * D_NODE * sizeof(__half);
    int use_f16 = (ws_size >= need_f16) ? 1 : 0;

    mega_setup<<<SETUP_GRID, 256, 0, stream>>>(
        nodes, nodes_h, use_f16, valW, Wih, Whh, valb, bih, bhh,
        qW, qb, keyW, keyb, Wbig2, binit, bvec4, M_, mkbuf);

    hist_query_kernel<<<SORTB + 625, 256, 0, stream>>>(
        dst, ph, gr, M_, mkbuf, blockhist, qk, qoff);

    colscan_kernel<<<(N_PART + 255) / 256, 256, 0, stream>>>(blockhist, totals);
    scan_kernel<<<1, 256, 0, stream>>>(totals, offsets);
    scatter_sorted_kernel<<<SORTB, 256, 0, stream>>>(src, dst, offsets, blockhist, ssrc);

    if (use_f16) {
        edge_agg_f16<<<N_PART, 256, 0, stream>>>(nodes_h, qk, qoff, offsets, ssrc, agg, att_sum);
    } else {
        edge_agg_f32<<<N_PART, 256, 0, stream>>>(nodes, qk, qoff, offsets, ssrc, agg, att_sum);
    }

    // hnew aliases qk (qk is dead after edge_agg)
    gru_gemm_v2<<<((N_PART + 31) / 32) * 4, 256, 0, stream>>>(
        agg, att_sum, ph, Wbig2, binit, bvec4, qk);

    epilogue_kernel<<<625, 256, 0, stream>>>(qk, ph, lng, lnb, W1, b1, W2, b2, out);
}